// Round 13
// baseline (159.983 us; speedup 1.0000x reference)
//
#include <hip/hip_runtime.h>
#include <hip/hip_bf16.h>
#include <stdint.h>

#define B_ROWS 4096
#define D_DIM  512
#define N2     8192
#define NBLK   64          // 8192 / 128
#define NTRI   (NBLK * (NBLK + 1) / 2)   // 2080 upper-tri blocks (2080 % 8 == 0)
#define BK     64          // fp8: 128x64 panel = 8 KB, same LDS as R7's bf16 BK=32

typedef __attribute__((ext_vector_type(4))) float f32x4;

// ---------------------------------------------------------------------------
// Kernel 1: row L2-norms, normalize, cast to fp8 e4m3 (OCP). Zeroes denom.
// 256 threads/row, each converts 2 floats via v_cvt_pk_fp8_f32.
// ---------------------------------------------------------------------------
__global__ void normalize_kernel(const float* __restrict__ zi,
                                 const float* __restrict__ zj,
                                 ushort* __restrict__ zn8,     // 2 fp8 per ushort
                                 float* __restrict__ denom) {
    const int row = blockIdx.x;         // 0..8191
    const int t   = threadIdx.x;        // 256 threads, one float2 each
    if (t == 0) denom[row] = 0.0f;
    const float* src = (row < B_ROWS) ? (zi + (size_t)row * D_DIM)
                                      : (zj + (size_t)(row - B_ROWS) * D_DIM);
    float2 v = ((const float2*)src)[t];
    float ss = v.x * v.x + v.y * v.y;
    #pragma unroll
    for (int off = 1; off < 64; off <<= 1) ss += __shfl_xor(ss, off);
    __shared__ float red[4];
    if ((t & 63) == 0) red[t >> 6] = ss;
    __syncthreads();
    const float tot = red[0] + red[1] + red[2] + red[3];
    const float inv = 1.0f / sqrtf(tot);   // norms ~22.6 >> eps
    // pack 2 normalized floats into 2 OCP e4m3 bytes (low half of result)
    const int packed = __builtin_amdgcn_cvt_pk_fp8_f32(v.x * inv, v.y * inv, 0, false);
    zn8[(size_t)row * (D_DIM / 2) + t] = (ushort)(packed & 0xFFFF);
}

// ---------------------------------------------------------------------------
// Kernel 2: R7 skeleton exactly (128x128 tile, 4 waves 2x2, simple
// stage->sync->MFMA->sync loop, linear LDS, T1 XCD swizzle, tri-decode),
// dtype bf16 -> fp8 e4m3 and BK 32 -> 64:
//   * per K-step staged bytes unchanged (8 KB A + 8 KB B), LDS 16 KB total
//   * 8 barrier-drains per block instead of 16
//   * L2/HBM traffic halved
// ---------------------------------------------------------------------------
__global__ __launch_bounds__(256) void gram_kernel(const uchar* __restrict__ zn8,
                                                   float* __restrict__ denom,
                                                   float* __restrict__ pos) {
    __shared__ uchar As[128 * BK];   // 8 KB
    __shared__ uchar Bs[128 * BK];   // 8 KB

    const int t    = threadIdx.x;
    const int lane = t & 63;
    const int wave = t >> 6;
    const int wr   = wave >> 1;       // wave-row quadrant (0..1)
    const int wc   = wave & 1;        // wave-col quadrant (0..1)

    // T1: XCD-chunked bijective swizzle (2080 = 8 * 260), then tri-decode
    const int g   = blockIdx.x;
    const int bid = (g & 7) * (NTRI / 8) + (g >> 3);
    int by = (int)((sqrtf(8.0f * (float)bid + 1.0f) - 1.0f) * 0.5f);
    while ((by * (by + 1)) / 2 > bid) --by;
    while (((by + 1) * (by + 2)) / 2 <= bid) ++by;
    const int bx = bid - (by * (by + 1)) / 2;
    const int row0 = bx * 128;
    const int col0 = by * 128;
    const bool offdiag = (bx != by);

    // staging: thread t covers (row = t>>2 [+64 per shot], colbyte = (t&3)*16)
    const int srow = t >> 2;          // 0..63
    const int scol = (t & 3) * 16;    // bytes

    f32x4 acc[4][4];
    #pragma unroll
    for (int m = 0; m < 4; ++m)
        #pragma unroll
        for (int n = 0; n < 4; ++n)
            acc[m][n] = (f32x4){0.f, 0.f, 0.f, 0.f};

    const int lrow_a = wr * 64 + (lane & 15);
    const int lrow_b = wc * 64 + (lane & 15);
    const int kgrp   = (lane >> 4) * 8;    // byte offset of lane's 8 fp8 elems

    for (int kt = 0; kt < D_DIM / BK; ++kt) {
        const int k0 = kt * BK;
        #pragma unroll
        for (int half = 0; half < 2; ++half) {
            const int r = srow + half * 64;
            const uchar* gA = zn8 + (size_t)(row0 + r) * D_DIM + k0 + scol;
            const uchar* gB = zn8 + (size_t)(col0 + r) * D_DIM + k0 + scol;
            __builtin_amdgcn_global_load_lds(
                (const __attribute__((address_space(1))) void*)gA,
                (__attribute__((address_space(3))) void*)(As + (size_t)(t + half * 256) * 16),
                16, 0, 0);
            __builtin_amdgcn_global_load_lds(
                (const __attribute__((address_space(1))) void*)gB,
                (__attribute__((address_space(3))) void*)(Bs + (size_t)(t + half * 256) * 16),
                16, 0, 0);
        }
        __syncthreads();   // compiler emits vmcnt(0)+lgkmcnt(0) drain

        // two K=32 slices per BK=64 step
        #pragma unroll
        for (int s = 0; s < 2; ++s) {
            long long af[4], bfr[4];
            #pragma unroll
            for (int m = 0; m < 4; ++m)
                af[m] = *(const long long*)(As + (size_t)(lrow_a + m * 16) * BK + s * 32 + kgrp);
            #pragma unroll
            for (int n = 0; n < 4; ++n)
                bfr[n] = *(const long long*)(Bs + (size_t)(lrow_b + n * 16) * BK + s * 32 + kgrp);

            #pragma unroll
            for (int m = 0; m < 4; ++m)
                #pragma unroll
                for (int n = 0; n < 4; ++n)
                    acc[m][n] = __builtin_amdgcn_mfma_f32_16x16x32_fp8_fp8(af[m], bfr[n], acc[m][n], 0, 0, 0);
        }
        __syncthreads();
    }

    // Epilogue: e = exp(2s) (diag masked); positives at gcol-grow==B;
    // row sums into denom[row]; col sums into denom[col] for off-diag blocks.
    const int colbase = col0 + wc * 64 + (lane & 15);
    float cs[4] = {0.f, 0.f, 0.f, 0.f};
    #pragma unroll
    for (int m = 0; m < 4; ++m) {
        const int rowbase = row0 + wr * 64 + m * 16 + (lane >> 4) * 4;
        float rs[4] = {0.f, 0.f, 0.f, 0.f};
        #pragma unroll
        for (int n = 0; n < 4; ++n) {
            const int gcol = colbase + n * 16;
            #pragma unroll
            for (int j = 0; j < 4; ++j) {
                const int grow = rowbase + j;
                const float s2 = 2.0f * acc[m][n][j];   // sim / T,  T = 0.5
                const float e  = (grow == gcol) ? 0.0f : __expf(s2);
                if (gcol - grow == B_ROWS) {            // +B diagonal (once per pair)
                    pos[grow] = s2;
                    pos[gcol] = s2;
                }
                rs[j] += e;
                cs[n] += e;
            }
        }
        #pragma unroll
        for (int off = 1; off < 16; off <<= 1) {
            rs[0] += __shfl_xor(rs[0], off);
            rs[1] += __shfl_xor(rs[1], off);
            rs[2] += __shfl_xor(rs[2], off);
            rs[3] += __shfl_xor(rs[3], off);
        }
        if ((lane & 15) == 0) {
            atomicAdd(&denom[rowbase + 0], rs[0]);
            atomicAdd(&denom[rowbase + 1], rs[1]);
            atomicAdd(&denom[rowbase + 2], rs[2]);
            atomicAdd(&denom[rowbase + 3], rs[3]);
        }
    }
    if (offdiag) {
        #pragma unroll
        for (int off = 16; off < 64; off <<= 1) {
            cs[0] += __shfl_xor(cs[0], off);
            cs[1] += __shfl_xor(cs[1], off);
            cs[2] += __shfl_xor(cs[2], off);
            cs[3] += __shfl_xor(cs[3], off);
        }
        if (lane < 16) {
            atomicAdd(&denom[colbase + 0],  cs[0]);
            atomicAdd(&denom[colbase + 16], cs[1]);
            atomicAdd(&denom[colbase + 32], cs[2]);
            atomicAdd(&denom[colbase + 48], cs[3]);
        }
    }
}

// ---------------------------------------------------------------------------
// Kernel 3: loss = mean( log(denom + 1e-8) - pos )
// ---------------------------------------------------------------------------
__global__ void loss_kernel(const float* __restrict__ denom,
                            const float* __restrict__ pos,
                            float* __restrict__ out) {
    const int t = threadIdx.x;      // 1024 threads
    float partial = 0.f;
    for (int i = t; i < N2; i += 1024)
        partial += logf(denom[i] + 1e-8f) - pos[i];
    #pragma unroll
    for (int off = 1; off < 64; off <<= 1) partial += __shfl_xor(partial, off);
    __shared__ float red[16];
    if ((t & 63) == 0) red[t >> 6] = partial;
    __syncthreads();
    if (t == 0) {
        float s = 0.f;
        #pragma unroll
        for (int i = 0; i < 16; ++i) s += red[i];
        out[0] = s * (1.0f / (float)N2);
    }
}

// ---------------------------------------------------------------------------
extern "C" void kernel_launch(void* const* d_in, const int* in_sizes, int n_in,
                              void* d_out, int out_size, void* d_ws, size_t ws_size,
                              hipStream_t stream) {
    const float* zi = (const float*)d_in[0];
    const float* zj = (const float*)d_in[1];
    char* ws = (char*)d_ws;
    ushort* zn8  = (ushort*)ws;                              // 8192*512 fp8 = 4 MB
    float* denom = (float*)(ws + (size_t)N2 * D_DIM);        // 8192 f32
    float* pos   = denom + N2;                               // 8192 f32
    float* out   = (float*)d_out;

    normalize_kernel<<<N2, 256, 0, stream>>>(zi, zj, zn8, denom);
    gram_kernel<<<NTRI, 256, 0, stream>>>((const uchar*)zn8, denom, pos);
    loss_kernel<<<1, 1024, 0, stream>>>(denom, pos, out);
}

// Round 14
// 120.774 us; speedup vs baseline: 1.3246x; 1.3246x over previous
//
#include <hip/hip_runtime.h>
#include <hip/hip_bf16.h>
#include <stdint.h>

#define B_ROWS 4096
#define D_DIM  512
#define N2     8192
#define NBLK   64          // 8192 / 128
#define NTRI   (NBLK * (NBLK + 1) / 2)   // 2080 upper-tri blocks (2080 % 8 == 0)
#define BK     64          // fp8: 128x64 panel = 8 KB, same LDS as R7's bf16 BK=32

typedef __attribute__((ext_vector_type(4))) float f32x4;

// ---------------------------------------------------------------------------
// Kernel 1: row L2-norms, normalize, cast to fp8 e4m3 (OCP). Zeroes denom.
// (unchanged from R13 — validated, absmax 0)
// ---------------------------------------------------------------------------
__global__ void normalize_kernel(const float* __restrict__ zi,
                                 const float* __restrict__ zj,
                                 ushort* __restrict__ zn8,     // 2 fp8 per ushort
                                 float* __restrict__ denom) {
    const int row = blockIdx.x;         // 0..8191
    const int t   = threadIdx.x;        // 256 threads, one float2 each
    if (t == 0) denom[row] = 0.0f;
    const float* src = (row < B_ROWS) ? (zi + (size_t)row * D_DIM)
                                      : (zj + (size_t)(row - B_ROWS) * D_DIM);
    float2 v = ((const float2*)src)[t];
    float ss = v.x * v.x + v.y * v.y;
    #pragma unroll
    for (int off = 1; off < 64; off <<= 1) ss += __shfl_xor(ss, off);
    __shared__ float red[4];
    if ((t & 63) == 0) red[t >> 6] = ss;
    __syncthreads();
    const float tot = red[0] + red[1] + red[2] + red[3];
    const float inv = 1.0f / sqrtf(tot);   // norms ~22.6 >> eps
    const int packed = __builtin_amdgcn_cvt_pk_fp8_f32(v.x * inv, v.y * inv, 0, false);
    zn8[(size_t)row * (D_DIM / 2) + t] = (ushort)(packed & 0xFFFF);
}

// ---------------------------------------------------------------------------
// Kernel 2: R13 fp8 gram + ONE change: 16B-chunk XOR swizzle (rule #21).
// LDS cell (row r, chunk c) holds global chunk c ^ g(r), g(r)=(r>>1)&3.
// Staging: linear gload_lds dest, source chunk pre-swizzled (coalescing kept:
// 4 threads still cover each 64B row). Readers: same XOR, lane-constant.
// Banks: 32 lanes -> 16 banks at 2-way = free (m136). Kills R13's 29.8M
// conflicts from the 64B-row-stride 8-way aliasing.
// ---------------------------------------------------------------------------
__global__ __launch_bounds__(256) void gram_kernel(const uchar* __restrict__ zn8,
                                                   float* __restrict__ denom,
                                                   float* __restrict__ pos) {
    __shared__ uchar As[128 * BK];   // 8 KB
    __shared__ uchar Bs[128 * BK];   // 8 KB

    const int t    = threadIdx.x;
    const int lane = t & 63;
    const int wave = t >> 6;
    const int wr   = wave >> 1;       // wave-row quadrant (0..1)
    const int wc   = wave & 1;        // wave-col quadrant (0..1)

    // T1: XCD-chunked bijective swizzle (2080 = 8 * 260), then tri-decode
    const int g   = blockIdx.x;
    const int bid = (g & 7) * (NTRI / 8) + (g >> 3);
    int by = (int)((sqrtf(8.0f * (float)bid + 1.0f) - 1.0f) * 0.5f);
    while ((by * (by + 1)) / 2 > bid) --by;
    while (((by + 1) * (by + 2)) / 2 <= bid) ++by;
    const int bx = bid - (by * (by + 1)) / 2;
    const int row0 = bx * 128;
    const int col0 = by * 128;
    const bool offdiag = (bx != by);

    // staging: thread t -> dest row t>>2 (+64/half), dest chunk t&3 (linear);
    // SOURCE chunk = (t&3) ^ g(row), g(row) = (row>>1)&3 = (t>>3)&3 (half-safe)
    const int srow = t >> 2;                                   // 0..63
    const int scol = (((t & 3) ^ ((t >> 3) & 3)) * 16);        // swizzled src bytes

    f32x4 acc[4][4];
    #pragma unroll
    for (int m = 0; m < 4; ++m)
        #pragma unroll
        for (int n = 0; n < 4; ++n)
            acc[m][n] = (f32x4){0.f, 0.f, 0.f, 0.f};

    const int lrow_a = wr * 64 + (lane & 15);
    const int lrow_b = wc * 64 + (lane & 15);
    const int hi     = lane >> 4;                 // 0..3
    const int g4     = ((lane & 15) >> 1) & 3;    // g(row) for this lane's rows

    for (int kt = 0; kt < D_DIM / BK; ++kt) {
        const int k0 = kt * BK;
        #pragma unroll
        for (int half = 0; half < 2; ++half) {
            const int r = srow + half * 64;
            const uchar* gA = zn8 + (size_t)(row0 + r) * D_DIM + k0 + scol;
            const uchar* gB = zn8 + (size_t)(col0 + r) * D_DIM + k0 + scol;
            __builtin_amdgcn_global_load_lds(
                (const __attribute__((address_space(1))) void*)gA,
                (__attribute__((address_space(3))) void*)(As + (size_t)(t + half * 256) * 16),
                16, 0, 0);
            __builtin_amdgcn_global_load_lds(
                (const __attribute__((address_space(1))) void*)gB,
                (__attribute__((address_space(3))) void*)(Bs + (size_t)(t + half * 256) * 16),
                16, 0, 0);
        }
        __syncthreads();   // compiler emits vmcnt(0)+lgkmcnt(0) drain

        // two K=32 slices per BK=64 step; lane's global chunk (2s + hi>>1)
        // lives in LDS chunk (2s + (hi>>1)) ^ g4, intra-chunk offset (hi&1)*8
        #pragma unroll
        for (int s = 0; s < 2; ++s) {
            const int ca = (((2 * s + (hi >> 1)) ^ g4) * 16) + (hi & 1) * 8;
            long long af[4], bfr[4];
            #pragma unroll
            for (int m = 0; m < 4; ++m)
                af[m] = *(const long long*)(As + (size_t)(lrow_a + m * 16) * BK + ca);
            #pragma unroll
            for (int n = 0; n < 4; ++n)
                bfr[n] = *(const long long*)(Bs + (size_t)(lrow_b + n * 16) * BK + ca);

            #pragma unroll
            for (int m = 0; m < 4; ++m)
                #pragma unroll
                for (int n = 0; n < 4; ++n)
                    acc[m][n] = __builtin_amdgcn_mfma_f32_16x16x32_fp8_fp8(af[m], bfr[n], acc[m][n], 0, 0, 0);
        }
        __syncthreads();
    }

    // Epilogue: e = exp(2s) (diag masked); positives at gcol-grow==B;
    // row sums into denom[row]; col sums into denom[col] for off-diag blocks.
    const int colbase = col0 + wc * 64 + (lane & 15);
    float cs[4] = {0.f, 0.f, 0.f, 0.f};
    #pragma unroll
    for (int m = 0; m < 4; ++m) {
        const int rowbase = row0 + wr * 64 + m * 16 + (lane >> 4) * 4;
        float rs[4] = {0.f, 0.f, 0.f, 0.f};
        #pragma unroll
        for (int n = 0; n < 4; ++n) {
            const int gcol = colbase + n * 16;
            #pragma unroll
            for (int j = 0; j < 4; ++j) {
                const int grow = rowbase + j;
                const float s2 = 2.0f * acc[m][n][j];   // sim / T,  T = 0.5
                const float e  = (grow == gcol) ? 0.0f : __expf(s2);
                if (gcol - grow == B_ROWS) {            // +B diagonal (once per pair)
                    pos[grow] = s2;
                    pos[gcol] = s2;
                }
                rs[j] += e;
                cs[n] += e;
            }
        }
        #pragma unroll
        for (int off = 1; off < 16; off <<= 1) {
            rs[0] += __shfl_xor(rs[0], off);
            rs[1] += __shfl_xor(rs[1], off);
            rs[2] += __shfl_xor(rs[2], off);
            rs[3] += __shfl_xor(rs[3], off);
        }
        if ((lane & 15) == 0) {
            atomicAdd(&denom[rowbase + 0], rs[0]);
            atomicAdd(&denom[rowbase + 1], rs[1]);
            atomicAdd(&denom[rowbase + 2], rs[2]);
            atomicAdd(&denom[rowbase + 3], rs[3]);
        }
    }
    if (offdiag) {
        #pragma unroll
        for (int off = 16; off < 64; off <<= 1) {
            cs[0] += __shfl_xor(cs[0], off);
            cs[1] += __shfl_xor(cs[1], off);
            cs[2] += __shfl_xor(cs[2], off);
            cs[3] += __shfl_xor(cs[3], off);
        }
        if (lane < 16) {
            atomicAdd(&denom[colbase + 0],  cs[0]);
            atomicAdd(&denom[colbase + 16], cs[1]);
            atomicAdd(&denom[colbase + 32], cs[2]);
            atomicAdd(&denom[colbase + 48], cs[3]);
        }
    }
}

// ---------------------------------------------------------------------------
// Kernel 3: loss = mean( log(denom + 1e-8) - pos )
// ---------------------------------------------------------------------------
__global__ void loss_kernel(const float* __restrict__ denom,
                            const float* __restrict__ pos,
                            float* __restrict__ out) {
    const int t = threadIdx.x;      // 1024 threads
    float partial = 0.f;
    for (int i = t; i < N2; i += 1024)
        partial += logf(denom[i] + 1e-8f) - pos[i];
    #pragma unroll
    for (int off = 1; off < 64; off <<= 1) partial += __shfl_xor(partial, off);
    __shared__ float red[16];
    if ((t & 63) == 0) red[t >> 6] = partial;
    __syncthreads();
    if (t == 0) {
        float s = 0.f;
        #pragma unroll
        for (int i = 0; i < 16; ++i) s += red[i];
        out[0] = s * (1.0f / (float)N2);
    }
}

// ---------------------------------------------------------------------------
extern "C" void kernel_launch(void* const* d_in, const int* in_sizes, int n_in,
                              void* d_out, int out_size, void* d_ws, size_t ws_size,
                              hipStream_t stream) {
    const float* zi = (const float*)d_in[0];
    const float* zj = (const float*)d_in[1];
    char* ws = (char*)d_ws;
    ushort* zn8  = (ushort*)ws;                              // 8192*512 fp8 = 4 MB
    float* denom = (float*)(ws + (size_t)N2 * D_DIM);        // 8192 f32
    float* pos   = denom + N2;                               // 8192 f32
    float* out   = (float*)d_out;

    normalize_kernel<<<N2, 256, 0, stream>>>(zi, zj, zn8, denom);
    gram_kernel<<<NTRI, 256, 0, stream>>>((const uchar*)zn8, denom, pos);
    loss_kernel<<<1, 1024, 0, stream>>>(denom, pos, out);
}